// Round 5
// baseline (169.743 us; speedup 1.0000x reference)
//
#include <hip/hip_runtime.h>
#include <hip/hip_bf16.h>
#include <stdint.h>

#define Hdim 512
#define KC   32768

typedef __hip_bfloat16 bf16;
typedef __attribute__((ext_vector_type(8))) short short8;
typedef __attribute__((ext_vector_type(4))) float float4v;

typedef const __attribute__((address_space(1))) void gvoid;
typedef __attribute__((address_space(3))) void svoid;

// pack two fp32 -> two bf16 (truncation) in one v_perm_b32
__device__ __forceinline__ unsigned int pack_bf16_trunc(float e0, float e1) {
  union { float f; unsigned int u; } a, b;
  a.f = e0; b.f = e1;
  return __builtin_amdgcn_perm(b.u, a.u, 0x07060302u);  // [hi16(e1):hi16(e0)]
}

__device__ __forceinline__ unsigned long long pack64(float4v v) {
  return (unsigned long long)pack_bf16_trunc(v[0], v[1])
       | ((unsigned long long)pack_bf16_trunc(v[2], v[3]) << 32);
}

// async global(per-lane addr) -> LDS(wave-uniform base + lane*16), 16B/lane
__device__ __forceinline__ void gload_lds16(const void* g, void* l) {
  __builtin_amdgcn_global_load_lds((gvoid*)g, (svoid*)l, 16, 0, 0);
}

// ---------------- launch 1: prep (blocks 0..31) + WT transpose (blocks 32..95) ----
__global__ __launch_bounds__(256) void prep_wt_kernel(
    const float* __restrict__ input_, const float* __restrict__ h_0,
    const float* __restrict__ w_ih, const float* __restrict__ w_hh,
    const float* __restrict__ a_w_ih, const float* __restrict__ a_w_hh,
    float* __restrict__ gates, float* __restrict__ awi, bf16* __restrict__ wt) {
  __shared__ float sh[64 * 65];
  const int t = threadIdx.x;
  const int b = blockIdx.x;
  if (b < 32) {
    const int lane = t & 63, wv = t >> 6;
    float* h0s = sh;           // 512
    float* ins = sh + 512;     // 512
    float* red = sh + 1024;    // 256
    for (int i = t; i < 512; i += 256) { h0s[i] = h_0[i]; ins[i] = input_[i]; }
    __syncthreads();
    float acc = 0.f;
    if (b < 24) {
      const int j = b * 64 + lane;
      const float* whh = w_hh + j;
      const float* wih = w_ih + j;
#pragma unroll 16
      for (int i = 0; i < 128; ++i) {
        const int d = wv * 128 + i;
        acc += h0s[d] * whh[(size_t)d * 1536] + ins[d] * wih[(size_t)d * 1536];
      }
    } else {
      const int j = (b - 24) * 64 + lane;
      const float* wai = a_w_ih + j;
#pragma unroll 16
      for (int i = 0; i < 128; ++i) {
        const int d = wv * 128 + i;
        acc += ins[d] * wai[(size_t)d * Hdim];
      }
    }
    red[wv * 64 + lane] = acc;
    __syncthreads();
    if (t < 64) {
      float s = red[t] + red[64 + t] + red[128 + t] + red[192 + t];
      if (b < 24) gates[b * 64 + t] = s;
      else        awi[(b - 24) * 64 + t] = s;
    }
  } else {
    // WT[h][d] = bf16(a_w_hh[d][h])
    const int bb = b - 32;
    const int d0 = (bb & 7) * 64, h0 = (bb >> 3) * 64;
    const int tx = t & 63, tw = t >> 6;
    float (*tile)[65] = (float (*)[65])sh;
#pragma unroll
    for (int r = 0; r < 16; ++r) {
      const int row = r * 4 + tw;
      tile[row][tx] = a_w_hh[(size_t)(d0 + row) * Hdim + h0 + tx];
    }
    __syncthreads();
#pragma unroll
    for (int r = 0; r < 16; ++r) {
      const int row = r * 4 + tw;
      wt[(size_t)(h0 + row) * Hdim + d0 + tx] = __float2bfloat16(tile[tx][row]);
    }
  }
}

// ---------------- launch 2: fused GEMM + sigmoid/exp + K-partial reduction ----------------
// 256 blocks (1/CU), 512 threads (8 waves, 2 kk-halves x 4 h-quarters).
// Each block owns kk=128 x ALL h=512 -> A (c_input) staged exactly ONCE
// (eliminates R3's 4x A-read amplification). A: reg-staged f32->bf16 pack into
// a single 16KB LDS tile (write between two barriers). B (WT, bf16): staged via
// global_load_lds into a 2x64KB double buffer, issued one full iteration ahead
// with pre-swizzled per-lane SOURCE addrs + linear LDS dest + swizzled read.
// The only vmcnt drain is __syncthreads' implicit one AFTER the compute phase.
__global__ __launch_bounds__(512, 2) void gemm_reduce_kernel(
    const float* __restrict__ c_input, const bf16* __restrict__ WT,
    const float* __restrict__ awi,
    float* __restrict__ pw, float* __restrict__ pwc) {
  __shared__ __align__(16) char pool[147456];   // A 16K | B0 64K | B1 64K
  char* const AsB = pool;
  char* const Bs0 = pool + 16384;
  char* const Bs1 = pool + 16384 + 65536;
  float* const red_w  = (float*)pool;           // alias A-buf after K-loop
  float* const red_wc = (float*)(pool + 4096);  // [2][512] each

  const int tid  = threadIdx.x;
  const int lane = tid & 63;
  const int wave = tid >> 6;      // 0..7
  const int wm   = wave & 1;      // kk half
  const int wn   = wave >> 1;     // h quarter (0..3)
  const int lm   = lane & 15;
  const int lq   = lane >> 4;

  const int kk_idx = blockIdx.x;  // 256 blocks
  const int kk0 = kk_idx * 128;

  // A staging: thread owns 16B f32 chunk 'sub' of rows rbase+32j (j=0..3)
  const int sub   = tid & 15;
  const int rbase = tid >> 4;     // 0..31
  const float* aglobS = c_input + (size_t)(kk0 + rbase) * Hdim + sub * 4;
  const int a_lds = rbase * 128 + (((sub >> 1) ^ (rbase & 7)) * 16) + (sub & 1) * 8;

  // B staging (global_load_lds): wave w stages rows 64w..64w+63 (8 insts of 1KB).
  // Lane l of inst j: row R = 64w+8j+(l>>3), dest granule l&7; source granule
  // (l&7)^(R&7) = (l&7)^(l>>3)  (inverse-swizzled source, linear dest).
  const bf16* bsrcS = WT + (size_t)(64 * wave + (lane >> 3)) * Hdim
                         + ((lane & 7) ^ (lane >> 3)) * 8;
  const int b_lds_wave = wave * 8192;   // byte offset of this wave's 8KB chunk

  float4v acc[4][8];
#pragma unroll
  for (int i = 0; i < 4; ++i)
#pragma unroll
    for (int j = 0; j < 8; ++j)
      acc[i][j] = (float4v){0.f, 0.f, 0.f, 0.f};

  // ---- prologue: stage tile 0 ----
#pragma unroll
  for (int j = 0; j < 8; ++j)
    gload_lds16(bsrcS + j * 8 * Hdim, Bs0 + b_lds_wave + j * 1024);
  {
    float4v ap[4];
#pragma unroll
    for (int j = 0; j < 4; ++j)
      ap[j] = *(const float4v*)(aglobS + (size_t)j * 32 * Hdim);
#pragma unroll
    for (int j = 0; j < 4; ++j)
      *(unsigned long long*)(AsB + j * 4096 + a_lds) = pack64(ap[j]);
  }
  __syncthreads();   // implicit vmcnt(0): B(0) landed, A(0) visible

  for (int t = 0; t < 8; ++t) {
    char* const BsR = (t & 1) ? Bs1 : Bs0;
    char* const BsW = (t & 1) ? Bs0 : Bs1;
    float4v ap[4];
    if (t < 7) {
      const int dn = (t + 1) * 64;
      // issue next B tile direct-to-LDS (no regs, floats across the barrier)
#pragma unroll
      for (int j = 0; j < 8; ++j)
        gload_lds16(bsrcS + j * 8 * Hdim + dn, BsW + b_lds_wave + j * 1024);
      // issue next A tile into regs
#pragma unroll
      for (int j = 0; j < 4; ++j)
        ap[j] = *(const float4v*)(aglobS + (size_t)j * 32 * Hdim + dn);
    }
    __builtin_amdgcn_sched_barrier(0);   // pin load issue before compute
    // ---- compute tile t ----
#pragma unroll
    for (int ks = 0; ks < 2; ++ks) {
      short8 a[4], bfr[8];
#pragma unroll
      for (int mt = 0; mt < 4; ++mt) {
        const int row = wm * 64 + mt * 16 + lm;
        a[mt] = *(const short8*)(AsB + row * 128 + (((ks * 4 + lq) ^ (lm & 7)) * 16));
      }
#pragma unroll
      for (int nt = 0; nt < 8; ++nt) {
        const int row = wn * 128 + nt * 16 + lm;
        bfr[nt] = *(const short8*)(BsR + row * 128 + (((ks * 4 + lq) ^ (lm & 7)) * 16));
      }
#pragma unroll
      for (int mt = 0; mt < 4; ++mt)
#pragma unroll
        for (int nt = 0; nt < 8; ++nt)
          acc[mt][nt] = __builtin_amdgcn_mfma_f32_16x16x32_bf16(
              a[mt], bfr[nt], acc[mt][nt], 0, 0, 0);
    }
    __syncthreads();   // reads of AsB done; drains vmcnt -> B(t+1)/A(t+1) landed
    if (t < 7) {       // write next A tile into the (single) A buffer
#pragma unroll
      for (int j = 0; j < 4; ++j)
        *(unsigned long long*)(AsB + j * 4096 + a_lds) = pack64(ap[j]);
    }
    __syncthreads();   // A(t+1) visible
  }

  // epilogue: alpha = sigmoid(acc + awi[h]); accumulate exp(alpha), exp(alpha)*c
  float awi_l[8];
#pragma unroll
  for (int nt = 0; nt < 8; ++nt)
    awi_l[nt] = awi[wn * 128 + nt * 16 + lm];

  float sw[8], swc[8];
#pragma unroll
  for (int nt = 0; nt < 8; ++nt) { sw[nt] = 0.f; swc[nt] = 0.f; }
#pragma unroll
  for (int nt = 0; nt < 8; ++nt) {
    const int h = wn * 128 + nt * 16 + lm;
#pragma unroll
    for (int mt = 0; mt < 4; ++mt) {
      const int kkb = kk0 + wm * 64 + mt * 16 + lq * 4;
#pragma unroll
      for (int r = 0; r < 4; ++r) {
        float v = acc[mt][nt][r] + awi_l[nt];
        float aval = 1.f / (1.f + __expf(-v));
        float e = __expf(aval);
        float c = c_input[(size_t)(kkb + r) * Hdim + h];  // L2-hot after GEMM pass
        sw[nt]  += e;
        swc[nt] += e * c;
      }
    }
  }
#pragma unroll
  for (int nt = 0; nt < 8; ++nt) {
    sw[nt]  += __shfl_xor(sw[nt], 16, 64);
    sw[nt]  += __shfl_xor(sw[nt], 32, 64);
    swc[nt] += __shfl_xor(swc[nt], 16, 64);
    swc[nt] += __shfl_xor(swc[nt], 32, 64);
  }
  if (lq == 0) {
#pragma unroll
    for (int nt = 0; nt < 8; ++nt) {
      red_w[wm * 512 + wn * 128 + nt * 16 + lm]  = sw[nt];
      red_wc[wm * 512 + wn * 128 + nt * 16 + lm] = swc[nt];
    }
  }
  __syncthreads();
  // 512 threads: one h each
  pw[(size_t)kk_idx * Hdim + tid]  = red_w[tid] + red_w[512 + tid];
  pwc[(size_t)kk_idx * Hdim + tid] = red_wc[tid] + red_wc[512 + tid];
}

// ---------------- launch 3: final reduction + LSTM merge ----------------
__global__ __launch_bounds__(256) void finalize_kernel(
    const float* __restrict__ pw, const float* __restrict__ pwc,
    const float* __restrict__ gates, const float* __restrict__ bias,
    float* __restrict__ out) {
  __shared__ float rsw[8][32], rswc[8][32];
  const int t = threadIdx.x;
  const int hl = t & 31, q = t >> 5;
  const int hh = blockIdx.x * 32 + hl;
  float sw = 0.f, swc = 0.f;
#pragma unroll 8
  for (int kb = q * 32; kb < q * 32 + 32; ++kb) {
    sw  += pw[(size_t)kb * Hdim + hh];
    swc += pwc[(size_t)kb * Hdim + hh];
  }
  rsw[q][hl] = sw; rswc[q][hl] = swc;
  __syncthreads();
  if (t < 32) {
    const int h = blockIdx.x * 32 + t;
    sw = 0.f; swc = 0.f;
#pragma unroll
    for (int q2 = 0; q2 < 8; ++q2) { sw += rsw[q2][t]; swc += rswc[q2][t]; }
    float ipre = gates[h] + bias[h];
    float opre = gates[Hdim + h] + bias[Hdim + h];
    float gpre = gates[2 * Hdim + h] + bias[2 * Hdim + h];
    float ei = expf(1.f / (1.f + expf(-ipre)));   // exp(sigmoid(i))
    float g  = tanhf(gpre);
    float o  = 1.f / (1.f + expf(-opre));
    float denom = ei + sw + 1e-12f;
    float c1 = (ei * g + swc) / denom;
    float h1 = o * tanhf(c1);
    out[h]        = h1;
    out[Hdim + h] = c1;
  }
}

extern "C" void kernel_launch(void* const* d_in, const int* in_sizes, int n_in,
                              void* d_out, int out_size, void* d_ws, size_t ws_size,
                              hipStream_t stream) {
  const float* input_  = (const float*)d_in[0];
  const float* c_input = (const float*)d_in[1];
  const float* h_0     = (const float*)d_in[2];
  /* d_in[3] = c_0: unused by the reference's taken branch */
  const float* w_ih    = (const float*)d_in[4];
  const float* w_hh    = (const float*)d_in[5];
  const float* bias    = (const float*)d_in[6];
  const float* a_w_ih  = (const float*)d_in[7];
  const float* a_w_hh  = (const float*)d_in[8];

  char* ws = (char*)d_ws;
  float* pw    = (float*)ws;                          // 256*512 f32 = 512 KB
  float* pwc   = (float*)(ws + 512 * 1024);           // 512 KB
  float* gates = (float*)(ws + 1024 * 1024);          // 6 KB
  float* awi   = (float*)(ws + 1024 * 1024 + 6144);   // 2 KB
  bf16*  WT    = (bf16*)(ws + 1024 * 1024 + 8192);    // 512 KB

  hipLaunchKernelGGL(prep_wt_kernel, dim3(96), dim3(256), 0, stream,
                     input_, h_0, w_ih, w_hh, a_w_ih, a_w_hh, gates, awi, WT);
  hipLaunchKernelGGL(gemm_reduce_kernel, dim3(256), dim3(512), 0, stream,
                     c_input, WT, awi, pw, pwc);
  hipLaunchKernelGGL(finalize_kernel, dim3(16), dim3(256), 0, stream,
                     pw, pwc, gates, bias, (float*)d_out);
}